// Round 1
// baseline (239.645 us; speedup 1.0000x reference)
//
#include <hip/hip_runtime.h>

namespace {
constexpr int Bn = 8;
constexpr int Ln = 2048;
constexpr int Dn = 64;
constexpr float EPS = 1e-8f;
constexpr int PAD = 68;   // LDS row stride in floats: 272 B, 16B-aligned, conflict-benign
}

// ---------------- Kernel 1: x @ {B,C,V}_w^T + bias ----------------
// grid 256 blocks x 512 threads; block handles 64 rows of the flat (B*L, 64) input.
__global__ __launch_bounds__(512) void proj_kernel(
    const float* __restrict__ x,
    const float* __restrict__ Bw, const float* __restrict__ Bb,
    const float* __restrict__ Cw, const float* __restrict__ Cb,
    const float* __restrict__ Vw, const float* __restrict__ Vb,
    float* __restrict__ BZ, float* __restrict__ CZ, float* __restrict__ VZ)
{
    __shared__ float xs[64][65];   // xs[local_row][d]
    __shared__ float Bt[64][65];   // Bt[d][e] = Bw[e][d]
    __shared__ float Ct[64][65];
    __shared__ float Vt[64][65];
    const int tid = threadIdx.x;
    const long long r0 = (long long)blockIdx.x * 64;   // flat row base
    for (int i = 0; i < 8; ++i) {
        int f = i * 512 + tid;        // 0..4095
        int e = f >> 6, d = f & 63;
        Bt[d][e] = Bw[f];
        Ct[d][e] = Cw[f];
        Vt[d][e] = Vw[f];
        xs[e][d]  = x[r0 * 64 + f];   // e doubles as local row index here
    }
    __syncthreads();
    const int e  = tid & 63;
    const int lw = tid >> 6;          // 0..7 -> rows lw*8 .. +7
    const int lbase = lw * 8;
    const float bb = Bb[e], cb = Cb[e], vb = Vb[e];
    float aB[8], aC[8], aV[8];
    #pragma unroll
    for (int j = 0; j < 8; ++j) { aB[j] = bb; aC[j] = cb; aV[j] = vb; }
    for (int d = 0; d < 64; ++d) {
        const float wB = Bt[d][e], wC = Ct[d][e], wV = Vt[d][e];
        #pragma unroll
        for (int j = 0; j < 8; ++j) {
            const float xv = xs[lbase + j][d];
            aB[j] += xv * wB; aC[j] += xv * wC; aV[j] += xv * wV;
        }
    }
    #pragma unroll
    for (int j = 0; j < 8; ++j) {
        const long long g = (r0 + lbase + j) * 64 + e;
        BZ[g] = aB[j]; CZ[g] = aC[j]; VZ[g] = aV[j];
    }
}

// ---------------- Kernel 2: partial column denominators ----------------
// denp[half][b][m] = sum over l in half of relu(BZ[b,l,:] . CZ[b,m,:])
// grid (32 m-tiles, 8 b, 2 l-halves) x 512 threads. Per-thread 4m x 4l register tile.
__global__ __launch_bounds__(512) void denom_kernel(
    const float* __restrict__ BZ, const float* __restrict__ CZ,
    float* __restrict__ denp)
{
    __shared__ float Ct2[64][PAD];      // [d][m_local]
    __shared__ float BZt[2][64][PAD];   // [chunk][d][l_local]
    const int tid = threadIdx.x;
    const int m0  = blockIdx.x * 64;
    const int b   = blockIdx.y;
    const int half = blockIdx.z;
    const long long cb0 = ((long long)b * Ln + m0) * 64;
    for (int i = 0; i < 8; ++i) {
        int f = i * 512 + tid;          // 0..4095
        Ct2[f & 63][f >> 6] = CZ[cb0 + f];
    }
    const int mg = tid & 15;            // m = m0 + mg*4 ..+3
    const int lg = (tid >> 4) & 15;     // l-in-chunk = lg*4 ..+3
    const int ch = tid >> 8;            // 0/1
    float acc[4] = {0.f, 0.f, 0.f, 0.f};
    __syncthreads();
    for (int outer = 0; outer < 8; ++outer) {
        const int lb = half * 1024 + outer * 128;
        const long long gb = ((long long)b * Ln + lb) * 64;
        __syncthreads();                 // previous iteration's reads complete
        for (int i = 0; i < 16; ++i) {
            int f = i * 512 + tid;       // 0..8191
            int l = f >> 6;              // 0..127
            BZt[l >> 6][f & 63][l & 63] = BZ[gb + f];
        }
        __syncthreads();
        float s[4][4];
        #pragma unroll
        for (int i = 0; i < 4; ++i)
            #pragma unroll
            for (int j = 0; j < 4; ++j) s[i][j] = 0.f;
        for (int d = 0; d < 64; ++d) {
            const float4 bl = *(const float4*)&BZt[ch][d][lg * 4];
            const float4 cm = *(const float4*)&Ct2[d][mg * 4];
            const float blv[4] = {bl.x, bl.y, bl.z, bl.w};
            const float cmv[4] = {cm.x, cm.y, cm.z, cm.w};
            #pragma unroll
            for (int i = 0; i < 4; ++i)
                #pragma unroll
                for (int j = 0; j < 4; ++j)
                    s[i][j] += blv[i] * cmv[j];
        }
        #pragma unroll
        for (int i = 0; i < 4; ++i)
            #pragma unroll
            for (int j = 0; j < 4; ++j)
                acc[j] += fmaxf(s[i][j], 0.f);
    }
    __syncthreads();
    // reduce partial column sums across the 32 (lg,ch) slots per m
    float* red = &BZt[0][0][0];          // reuse as [64 m][33]
    const int slot = tid >> 4;           // 0..31
    #pragma unroll
    for (int j = 0; j < 4; ++j)
        red[(mg * 4 + j) * 33 + slot] = acc[j];
    __syncthreads();
    if (tid < 64) {
        float t = 0.f;
        for (int k = 0; k < 32; ++k) t += red[tid * 33 + k];
        denp[((long long)half * Bn + b) * Ln + m0 + tid] = t;
    }
}

// ---------------- Kernel 3: scores + normalize + PV + residual ----------------
// grid (32 l-tiles, 8 b) x 512 threads; l-tile = 64 rows; m in superchunks of 128.
__global__ __launch_bounds__(512) void out_kernel(
    const float* __restrict__ x,
    const float* __restrict__ BZ, const float* __restrict__ CZ,
    const float* __restrict__ VZ, const float* __restrict__ denp,
    float* __restrict__ out)
{
    __shared__ float BZt[64][PAD];       // [d][l_local]
    __shared__ float Ct2[2][64][PAD];    // [ch][d][m_local]
    __shared__ float VZs[2][64][PAD];    // [ch][m_local][d]
    __shared__ float Sm [2][64][PAD];    // [ch][m_local][l_local]  relu'd*1/den
    __shared__ float denl[128];
    const int tid = threadIdx.x;
    const int l0 = blockIdx.x * 64;
    const int b  = blockIdx.y;
    const long long lb0 = ((long long)b * Ln + l0) * 64;
    for (int i = 0; i < 8; ++i) {
        int f = i * 512 + tid;
        BZt[f & 63][f >> 6] = BZ[lb0 + f];
    }
    const int mg = tid & 15;
    const int lg = (tid >> 4) & 15;
    const int ch = tid >> 8;
    const int dB = tid & 63;
    const int wv = tid >> 6;             // 0..7 -> rows wv*8..+7
    float acc[8];
    #pragma unroll
    for (int j = 0; j < 8; ++j) acc[j] = 0.f;
    __syncthreads();
    for (int m0 = 0; m0 < Ln; m0 += 128) {
        const long long cb0 = ((long long)b * Ln + m0) * 64;
        __syncthreads();                 // prev phase B done with Ct2/VZs/Sm
        if (tid < 128)
            denl[tid] = 1.f / (denp[(long long)b * Ln + m0 + tid]
                             + denp[((long long)(Bn + b)) * Ln + m0 + tid] + EPS);
        for (int i = 0; i < 16; ++i) {
            int f  = i * 512 + tid;      // 0..8191
            int mf = f >> 6;             // 0..127
            int d  = f & 63;
            float cv = CZ[cb0 + f];
            float vv = VZ[cb0 + f];
            Ct2[mf >> 6][d][mf & 63] = cv;
            VZs[mf >> 6][mf & 63][d] = vv;
        }
        __syncthreads();
        // phase A: S tile (64l x 64m per ch), 4x4 per thread
        float s[4][4];
        #pragma unroll
        for (int i = 0; i < 4; ++i)
            #pragma unroll
            for (int j = 0; j < 4; ++j) s[i][j] = 0.f;
        for (int d = 0; d < 64; ++d) {
            const float4 bl = *(const float4*)&BZt[d][lg * 4];
            const float4 cm = *(const float4*)&Ct2[ch][d][mg * 4];
            const float blv[4] = {bl.x, bl.y, bl.z, bl.w};
            const float cmv[4] = {cm.x, cm.y, cm.z, cm.w};
            #pragma unroll
            for (int i = 0; i < 4; ++i)
                #pragma unroll
                for (int j = 0; j < 4; ++j)
                    s[i][j] += blv[i] * cmv[j];
        }
        #pragma unroll
        for (int j = 0; j < 4; ++j) {
            const float rd = denl[ch * 64 + mg * 4 + j];
            float4 w;
            w.x = fmaxf(s[0][j], 0.f) * rd;
            w.y = fmaxf(s[1][j], 0.f) * rd;
            w.z = fmaxf(s[2][j], 0.f) * rd;
            w.w = fmaxf(s[3][j], 0.f) * rd;
            *(float4*)&Sm[ch][mg * 4 + j][lg * 4] = w;
        }
        __syncthreads();
        // phase B: out[l][d] += Sm[m][l] * VZ[m][d]
        for (int c2 = 0; c2 < 2; ++c2) {
            for (int m = 0; m < 64; ++m) {
                const float vz = VZs[c2][m][dB];
                const float4 s0 = *(const float4*)&Sm[c2][m][wv * 8];
                const float4 s1 = *(const float4*)&Sm[c2][m][wv * 8 + 4];
                acc[0] += s0.x * vz; acc[1] += s0.y * vz;
                acc[2] += s0.z * vz; acc[3] += s0.w * vz;
                acc[4] += s1.x * vz; acc[5] += s1.y * vz;
                acc[6] += s1.z * vz; acc[7] += s1.w * vz;
            }
        }
    }
    #pragma unroll
    for (int j = 0; j < 8; ++j) {
        const long long g = lb0 + (long long)(wv * 8 + j) * 64 + dB;
        out[g] = x[g] + acc[j];
    }
}

extern "C" void kernel_launch(void* const* d_in, const int* in_sizes, int n_in,
                              void* d_out, int out_size, void* d_ws, size_t ws_size,
                              hipStream_t stream) {
    const float* x  = (const float*)d_in[0];
    const float* Bw = (const float*)d_in[1];
    const float* Bb = (const float*)d_in[2];
    const float* Cw = (const float*)d_in[3];
    const float* Cb = (const float*)d_in[4];
    const float* Vw = (const float*)d_in[5];
    const float* Vb = (const float*)d_in[6];
    float* out = (float*)d_out;
    float* ws  = (float*)d_ws;
    float* BZ = ws;                    // B*L*D floats
    float* CZ = ws + (1 << 20);
    float* VZ = ws + (2 << 20);
    float* dp = ws + (3 << 20);        // [2][B][L] partial denominators

    proj_kernel<<<dim3(256), 512, 0, stream>>>(x, Bw, Bb, Cw, Cb, Vw, Vb, BZ, CZ, VZ);
    denom_kernel<<<dim3(32, 8, 2), 512, 0, stream>>>(BZ, CZ, dp);
    out_kernel<<<dim3(32, 8), 512, 0, stream>>>(x, BZ, CZ, VZ, dp, out);
}

// Round 2
// 56.297 us; speedup vs baseline: 4.2568x; 4.2568x over previous
//
#include <hip/hip_runtime.h>

typedef unsigned short u16;
typedef unsigned int u32;
typedef __bf16 bf16x8 __attribute__((ext_vector_type(8)));
typedef float f32x16 __attribute__((ext_vector_type(16)));
typedef const void __attribute__((address_space(1))) gvoid;
typedef void __attribute__((address_space(3))) lvoid;

#define GLOAD16(gp, lp) __builtin_amdgcn_global_load_lds((gvoid*)(gp), (lvoid*)(lp), 16, 0, 0)

namespace {
constexpr int Ln = 2048;
constexpr float EPS = 1e-8f;
}

__device__ __forceinline__ u16 f2bf(float f) {
  __bf16 h = (__bf16)f;
  return __builtin_bit_cast(u16, h);
}

// ---------------- Kernel 1: projections, fp32 compute -> bf16 out + VZ^T ----
__global__ __launch_bounds__(512) void proj_k(
    const float* __restrict__ x,
    const float* __restrict__ Bw, const float* __restrict__ Bb,
    const float* __restrict__ Cw, const float* __restrict__ Cb,
    const float* __restrict__ Vw, const float* __restrict__ Vb,
    u16* __restrict__ BZh, u16* __restrict__ CZh, u16* __restrict__ VZTh)
{
    __shared__ float xs[64][65];
    __shared__ float Bt[64][65];
    __shared__ float Ct[64][65];
    __shared__ float Vt[64][65];
    __shared__ float vt[64][68];   // f32 VZ^T staging, 16B-aligned rows
    const int tid = threadIdx.x;
    const int r0 = (int)blockIdx.x * 64;
    for (int i = 0; i < 8; ++i) {
        int f = i * 512 + tid;
        int e = f >> 6, d = f & 63;
        Bt[d][e] = Bw[f];
        Ct[d][e] = Cw[f];
        Vt[d][e] = Vw[f];
        xs[e][d] = x[r0 * 64 + f];
    }
    __syncthreads();
    const int e  = tid & 63;
    const int lbase = (tid >> 6) * 8;
    const float bb = Bb[e], cb = Cb[e], vb = Vb[e];
    float aB[8], aC[8], aV[8];
    #pragma unroll
    for (int j = 0; j < 8; ++j) { aB[j] = bb; aC[j] = cb; aV[j] = vb; }
    for (int d = 0; d < 64; ++d) {
        const float wB = Bt[d][e], wC = Ct[d][e], wV = Vt[d][e];
        #pragma unroll
        for (int j = 0; j < 8; ++j) {
            const float xv = xs[lbase + j][d];
            aB[j] += xv * wB; aC[j] += xv * wC; aV[j] += xv * wV;
        }
    }
    #pragma unroll
    for (int j = 0; j < 8; ++j) {
        const int g = (r0 + lbase + j) * 64 + e;
        BZh[g] = f2bf(aB[j]);
        CZh[g] = f2bf(aC[j]);
        vt[e][lbase + j] = aV[j];
    }
    __syncthreads();
    const int d  = tid >> 3;
    const int lc = (tid & 7) * 8;
    const int bq  = r0 >> 11;
    const int l0b = r0 & 2047;
    u16 pk8[8];
    #pragma unroll
    for (int t = 0; t < 8; ++t) pk8[t] = f2bf(vt[d][lc + t]);
    uint4 pv;
    pv.x = (u32)pk8[0] | ((u32)pk8[1] << 16);
    pv.y = (u32)pk8[2] | ((u32)pk8[3] << 16);
    pv.z = (u32)pk8[4] | ((u32)pk8[5] << 16);
    pv.w = (u32)pk8[6] | ((u32)pk8[7] << 16);
    *(uint4*)(VZTh + ((bq * 64 + d) * Ln + l0b + lc)) = pv;
}

// ---------------- Kernel 2: column denominators via MFMA ----------------
// colsum[b][m] = sum_l relu(BZ[b,l,:] . CZ[b,m,:])
__global__ __launch_bounds__(512) void denom_k(
    const u16* __restrict__ BZh, const u16* __restrict__ CZh,
    float* __restrict__ colsum)
{
    __shared__ __attribute__((aligned(16))) char smem2[16384 + 64 * 4 * 4];
    char* const BZs2 = smem2;
    float* const red = (float*)(smem2 + 16384);
    const int tid = threadIdx.x;
    const int lane = tid & 63;
    const int ln = lane & 31;
    const int g5 = lane >> 5;
    const int w  = tid >> 6;
    const int wm2 = w & 1, wl2 = w >> 1;
    const int b  = blockIdx.y;
    const int mb = blockIdx.x * 64;
    const int wave_base = tid & ~63;

    // A fragments (CZ rows) direct from global, hoisted
    bf16x8 af[4];
    {
        const int m = mb + wm2 * 32 + ln;
        const u16* cp = CZh + ((b * Ln + m) << 6) + g5 * 8;
        #pragma unroll
        for (int c = 0; c < 4; ++c) af[c] = *(const bf16x8*)(cp + c * 16);
    }
    float accs[16];
    #pragma unroll
    for (int r = 0; r < 16; ++r) accs[r] = 0.f;
    const int lrr = wl2 * 32 + ln;
    for (int lt0 = 0; lt0 < Ln; lt0 += 128) {
        __syncthreads();   // prior reads complete before restage
        #pragma unroll
        for (int it = 0; it < 2; ++it) {
            int j = (it << 9) + tid;
            int r = j >> 3;
            int u = (j & 7) ^ (r & 7);
            const u16* src = BZh + ((b * Ln + lt0 + r) << 6) + (u << 3);
            GLOAD16(src, BZs2 + ((it << 9) + wave_base) * 16);
        }
        __syncthreads();   // drains vmcnt: staged data visible
        f32x16 st = {};
        #pragma unroll
        for (int c = 0; c < 4; ++c) {
            int un = (c << 1) | g5;
            bf16x8 bfr = *(const bf16x8*)(BZs2 + (lrr << 7) + ((un ^ (lrr & 7)) << 4));
            st = __builtin_amdgcn_mfma_f32_32x32x16_bf16(af[c], bfr, st, 0, 0, 0);
        }
        #pragma unroll
        for (int r = 0; r < 16; ++r) accs[r] += fmaxf(st[r], 0.f);
    }
    // reduce over the 32 l-lanes of each half
    #pragma unroll
    for (int msk = 1; msk <= 16; msk <<= 1)
        #pragma unroll
        for (int r = 0; r < 16; ++r)
            accs[r] += __shfl_xor(accs[r], msk, 64);
    if (ln == 0) {
        #pragma unroll
        for (int r = 0; r < 16; ++r) {
            int mloc = wm2 * 32 + (r & 3) + ((r >> 2) << 3) + g5 * 4;
            red[mloc * 4 + wl2] = accs[r];
        }
    }
    __syncthreads();
    if (tid < 64)
        colsum[b * Ln + mb + tid] = red[tid*4+0] + red[tid*4+1] + red[tid*4+2] + red[tid*4+3];
}

// ---------------- Kernel 3: recompute S, normalize, PV, residual --------
__global__ __launch_bounds__(512) void fused_out(
    const float* __restrict__ x,
    const u16* __restrict__ BZh, const u16* __restrict__ CZh,
    const u16* __restrict__ VZTh, const float* __restrict__ colsum,
    float* __restrict__ out)
{
    // [0,8K) BZs  [8K,24K) P  [24K,32K) denl  [32K,64K) buf0  [64K,96K) buf1
    __shared__ __attribute__((aligned(16))) char smem[98304];
    char* const BZs = smem;
    char* const Pb  = smem + 8192;
    float* const denl = (float*)(smem + 24576);
    const int tid = threadIdx.x;
    const int lane = tid & 63;
    const int ln = lane & 31;
    const int g5 = lane >> 5;
    const int w  = tid >> 6;
    const int b  = blockIdx.y;
    const int l0 = blockIdx.x * 64;
    const int wave_base = tid & ~63;

    auto stage = [&](int m0s, int bi) {
        char* bufc = smem + 32768 + (bi << 15);
        char* vzb  = bufc + 16384;
        #pragma unroll
        for (int it = 0; it < 2; ++it) {             // CZ chunk [128 m][64 d]
            int j = (it << 9) + tid;
            int r = j >> 3;
            int u = (j & 7) ^ (r & 7);
            const u16* src = CZh + ((b * Ln + m0s + r) << 6) + (u << 3);
            GLOAD16(src, bufc + ((it << 9) + wave_base) * 16);
        }
        #pragma unroll
        for (int it = 0; it < 2; ++it) {             // VZT chunk [64 d][128 m]
            int j = (it << 9) + tid;
            int r = j >> 4;
            int u = (j & 15) ^ (r & 7);
            const u16* src = VZTh + ((b << 6) + r) * Ln + m0s + (u << 3);
            GLOAD16(src, vzb + ((it << 9) + wave_base) * 16);
        }
    };

    // prologue: BZ tile, denominators, chunk 0
    {
        int j = tid;
        int r = j >> 3;
        int u = (j & 7) ^ (r & 7);
        const u16* src = BZh + ((b * Ln + l0 + r) << 6) + (u << 3);
        GLOAD16(src, BZs + (wave_base << 4));
    }
    {
        const float4 cs = *(const float4*)(colsum + b * Ln + tid * 4);
        float4 dv;
        dv.x = 1.f / (cs.x + EPS); dv.y = 1.f / (cs.y + EPS);
        dv.z = 1.f / (cs.z + EPS); dv.w = 1.f / (cs.w + EPS);
        *(float4*)(denl + tid * 4) = dv;
    }
    stage(0, 0);
    __syncthreads();

    f32x16 acc = {};
    const int wm = w & 3, wl = w >> 2;          // phase A roles
    const int wt = w >> 1, ws2 = w & 1;         // phase B roles
    const int dt = wt >> 1, lt = wt & 1;
    const int mrA = wm * 32 + ln;
    const int lrA = wl * 32 + ln;
    const int drB = dt * 32 + ln;
    const int lrB = lt * 32 + ln;

    for (int cI = 0; cI < 16; ++cI) {
        const int cur = cI & 1;
        if (cI < 15) stage((cI + 1) << 7, cur ^ 1);
        const char* cz = smem + 32768 + (cur << 15);
        // ---- phase A: St = CZ . BZ^T, relu, scale, pack to P ----
        f32x16 st = {};
        #pragma unroll
        for (int c = 0; c < 4; ++c) {
            int un = (c << 1) | g5;
            bf16x8 a   = *(const bf16x8*)(cz  + (mrA << 7) + ((un ^ (mrA & 7)) << 4));
            bf16x8 bfr = *(const bf16x8*)(BZs + (lrA << 7) + ((un ^ (lrA & 7)) << 4));
            st = __builtin_amdgcn_mfma_f32_32x32x16_bf16(a, bfr, st, 0, 0, 0);
        }
        const int mbase = (cI << 7) + wm * 32;
        #pragma unroll
        for (int q = 0; q < 4; ++q) {
            const int mq = mbase + q * 8 + g5 * 4;
            float p0 = fmaxf(st[q*4+0], 0.f) * denl[mq + 0];
            float p1 = fmaxf(st[q*4+1], 0.f) * denl[mq + 1];
            float p2 = fmaxf(st[q*4+2], 0.f) * denl[mq + 2];
            float p3 = fmaxf(st[q*4+3], 0.f) * denl[mq + 3];
            uint2 pk;
            pk.x = (u32)f2bf(p0) | ((u32)f2bf(p1) << 16);
            pk.y = (u32)f2bf(p2) | ((u32)f2bf(p3) << 16);
            *(uint2*)(Pb + (lrA << 8) + ((((wm << 2) | q) ^ (lrA & 7)) << 4) + (g5 << 3)) = pk;
        }
        asm volatile("s_waitcnt lgkmcnt(0)" ::: "memory");
        __builtin_amdgcn_s_barrier();
        asm volatile("" ::: "memory");
        // ---- phase B: out^T += VZT . P^T  (K split over wave pairs) ----
        const char* vz = cz + 16384;
        #pragma unroll
        for (int c = 0; c < 4; ++c) {
            int un = (ws2 << 3) | (c << 1) | g5;
            bf16x8 av = *(const bf16x8*)(vz + (drB << 8) + ((un ^ (drB & 7)) << 4));
            bf16x8 bp = *(const bf16x8*)(Pb + (lrB << 8) + ((un ^ (lrB & 7)) << 4));
            acc = __builtin_amdgcn_mfma_f32_32x32x16_bf16(av, bp, acc, 0, 0, 0);
        }
        asm volatile("s_waitcnt vmcnt(0) lgkmcnt(0)" ::: "memory");
        __builtin_amdgcn_s_barrier();
        asm volatile("" ::: "memory");
    }

    // K-split reduction + residual + store
    __syncthreads();
    float* redf = (float*)(smem + 32768);
    if (ws2 == 1) {
        #pragma unroll
        for (int r = 0; r < 16; ++r) redf[(wt * 64 + lane) * 17 + r] = acc[r];
    }
    __syncthreads();
    if (ws2 == 0) {
        #pragma unroll
        for (int r = 0; r < 16; ++r) acc[r] += redf[(wt * 64 + lane) * 17 + r];
        const int row = b * Ln + l0 + lt * 32 + ln;
        #pragma unroll
        for (int q = 0; q < 4; ++q) {
            const int d = dt * 32 + q * 8 + g5 * 4;
            const float4 xv = *(const float4*)(x + row * 64 + d);
            float4 o;
            o.x = xv.x + acc[q*4+0];
            o.y = xv.y + acc[q*4+1];
            o.z = xv.z + acc[q*4+2];
            o.w = xv.w + acc[q*4+3];
            *(float4*)(out + row * 64 + d) = o;
        }
    }
}

extern "C" void kernel_launch(void* const* d_in, const int* in_sizes, int n_in,
                              void* d_out, int out_size, void* d_ws, size_t ws_size,
                              hipStream_t stream) {
    const float* x  = (const float*)d_in[0];
    const float* Bw = (const float*)d_in[1];
    const float* Bb = (const float*)d_in[2];
    const float* Cw = (const float*)d_in[3];
    const float* Cb = (const float*)d_in[4];
    const float* Vw = (const float*)d_in[5];
    const float* Vb = (const float*)d_in[6];
    float* out = (float*)d_out;
    char* wsb = (char*)d_ws;
    u16* BZh  = (u16*)wsb;                       // 2 MB
    u16* CZh  = (u16*)(wsb + (2u << 20));        // 2 MB
    u16* VZTh = (u16*)(wsb + (4u << 20));        // 2 MB
    float* colsum = (float*)(wsb + (6u << 20));  // 64 KB

    proj_k<<<dim3(256), 512, 0, stream>>>(x, Bw, Bb, Cw, Cb, Vw, Vb, BZh, CZh, VZTh);
    denom_k<<<dim3(32, 8), 512, 0, stream>>>(BZh, CZh, colsum);
    fused_out<<<dim3(32, 8), 512, 0, stream>>>(x, BZh, CZh, VZTh, colsum, out);
}

// Round 4
// 53.812 us; speedup vs baseline: 4.4533x; 1.0462x over previous
//
#include <hip/hip_runtime.h>

typedef unsigned short u16;
typedef unsigned int u32;
typedef __bf16 bf16x8 __attribute__((ext_vector_type(8)));
typedef float f32x16 __attribute__((ext_vector_type(16)));
typedef const void __attribute__((address_space(1))) gvoid;
typedef void __attribute__((address_space(3))) lvoid;

#define GLOAD16(gp, lp) __builtin_amdgcn_global_load_lds((gvoid*)(gp), (lvoid*)(lp), 16, 0, 0)
// compiler fence after raw s_barrier: s_barrier is IntrNoMem, LDS reads may
// otherwise hoist above it and race other waves' in-flight global_load_lds.
#define POST_BARRIER_FENCE() do { __builtin_amdgcn_sched_barrier(0); asm volatile("" ::: "memory"); } while (0)

namespace {
constexpr int Ln = 2048;
constexpr float EPS = 1e-8f;
}

__device__ __forceinline__ u16 f2bf(float f) {
  __bf16 h = (__bf16)f;
  return __builtin_bit_cast(u16, h);
}

__device__ __forceinline__ u32 pk2(float lo, float hi) {
    u32 r;
    asm("v_cvt_pk_bf16_f32 %0, %1, %2" : "=v"(r) : "v"(lo), "v"(hi));
    return r;
}

// half_swap semantics: na[l<32] = b[l+32], na[l>=32] = a[l];
//                      nb[l<32] = b[l],    nb[l>=32] = a[l-32]
// Unambiguous shfl-based implementation (permlane32_swap A/B later).
__device__ __forceinline__ void half_swap(u32 a, u32 b, u32& na, u32& nb) {
    u32 sa = (u32)__shfl_xor((int)a, 32, 64);
    u32 sb = (u32)__shfl_xor((int)b, 32, 64);
    int hi = (threadIdx.x & 63) >> 5;
    na = hi ? a : sb;
    nb = hi ? sa : b;
}

// ---------------- Kernel 1: projections, fp32 compute -> bf16 out + VZ^T ----
__global__ __launch_bounds__(512) void proj_k(
    const float* __restrict__ x,
    const float* __restrict__ Bw, const float* __restrict__ Bb,
    const float* __restrict__ Cw, const float* __restrict__ Cb,
    const float* __restrict__ Vw, const float* __restrict__ Vb,
    u16* __restrict__ BZh, u16* __restrict__ CZh, u16* __restrict__ VZTh)
{
    __shared__ float xs[64][65];
    __shared__ float Bt[64][65];
    __shared__ float Ct[64][65];
    __shared__ float Vt[64][65];
    __shared__ float vt[64][68];
    const int tid = threadIdx.x;
    const int r0 = (int)blockIdx.x * 64;
    for (int i = 0; i < 8; ++i) {
        int f = i * 512 + tid;
        int e = f >> 6, d = f & 63;
        Bt[d][e] = Bw[f];
        Ct[d][e] = Cw[f];
        Vt[d][e] = Vw[f];
        xs[e][d] = x[r0 * 64 + f];
    }
    __syncthreads();
    const int e  = tid & 63;
    const int lbase = (tid >> 6) * 8;
    const float bb = Bb[e], cb = Cb[e], vb = Vb[e];
    float aB[8], aC[8], aV[8];
    #pragma unroll
    for (int j = 0; j < 8; ++j) { aB[j] = bb; aC[j] = cb; aV[j] = vb; }
    for (int d = 0; d < 64; ++d) {
        const float wB = Bt[d][e], wC = Ct[d][e], wV = Vt[d][e];
        #pragma unroll
        for (int j = 0; j < 8; ++j) {
            const float xv = xs[lbase + j][d];
            aB[j] += xv * wB; aC[j] += xv * wC; aV[j] += xv * wV;
        }
    }
    #pragma unroll
    for (int j = 0; j < 8; ++j) {
        const int g = (r0 + lbase + j) * 64 + e;
        BZh[g] = f2bf(aB[j]);
        CZh[g] = f2bf(aC[j]);
        vt[e][lbase + j] = aV[j];
    }
    __syncthreads();
    const int d  = tid >> 3;
    const int lc = (tid & 7) * 8;
    const int bq  = r0 >> 11;
    const int l0b = r0 & 2047;
    u16 pk8[8];
    #pragma unroll
    for (int t = 0; t < 8; ++t) pk8[t] = f2bf(vt[d][lc + t]);
    uint4 pv;
    pv.x = (u32)pk8[0] | ((u32)pk8[1] << 16);
    pv.y = (u32)pk8[2] | ((u32)pk8[3] << 16);
    pv.z = (u32)pk8[4] | ((u32)pk8[5] << 16);
    pv.w = (u32)pk8[6] | ((u32)pk8[7] << 16);
    *(uint4*)(VZTh + ((bq * 64 + d) * Ln + l0b + lc)) = pv;
}

// ---------------- Kernel 2: partial column denominators via MFMA ----------
// denp[half][b][m] = sum over l-half of relu(BZ[b,l,:] . CZ[b,m,:])
__global__ __launch_bounds__(512) void denom_k(
    const u16* __restrict__ BZh, const u16* __restrict__ CZh,
    float* __restrict__ denp)
{
    __shared__ __attribute__((aligned(16))) char smem2[49152 + 1024];
    float* const red = (float*)(smem2 + 49152);
    const int tid = threadIdx.x;
    const int lane = tid & 63;
    const int ln = lane & 31;
    const int g5 = lane >> 5;
    const int w = tid >> 6;
    const int wm2 = w & 1, wl2 = w >> 1;     // 2 m-tiles x 4 l-subtiles
    const int b = blockIdx.y;
    const int mb = blockIdx.x * 64;
    const int half = blockIdx.z;
    const int l0h = half * 1024;
    const int wave_base = tid & ~63;

    bf16x8 af[4];
    {
        const u16* cp = CZh + ((b * Ln + mb + wm2 * 32 + ln) << 6) + g5 * 8;
        #pragma unroll
        for (int c = 0; c < 4; ++c) af[c] = *(const bf16x8*)(cp + c * 16);
    }
    auto stageD = [&](int t) {
        char* buf = smem2 + (t % 3) * 16384;
        #pragma unroll
        for (int it = 0; it < 2; ++it) {
            int j = (it << 9) + tid;
            int r = j >> 3;
            int u = (j & 7) ^ (r & 7);
            GLOAD16(BZh + ((b * Ln + l0h + t * 128 + r) << 6) + (u << 3),
                    buf + ((it << 9) + wave_base) * 16);
        }
    };
    stageD(0); stageD(1);
    __syncthreads();
    float accs[16];
    #pragma unroll
    for (int r = 0; r < 16; ++r) accs[r] = 0.f;
    const int lr = wl2 * 32 + ln;
    for (int t = 0; t < 8; ++t) {
        if (t > 0) {
            if (t < 7) asm volatile("s_waitcnt vmcnt(2)" ::: "memory");
            else       asm volatile("s_waitcnt vmcnt(0)" ::: "memory");
            __builtin_amdgcn_s_barrier();
            POST_BARRIER_FENCE();
        }
        if (t + 2 < 8) stageD(t + 2);
        const char* buf = smem2 + (t % 3) * 16384;
        f32x16 st = {};
        __builtin_amdgcn_s_setprio(1);
        #pragma unroll
        for (int c = 0; c < 4; ++c) {
            int un = (c << 1) | g5;
            bf16x8 bfr = *(const bf16x8*)(buf + (lr << 7) + ((un ^ (lr & 7)) << 4));
            st = __builtin_amdgcn_mfma_f32_32x32x16_bf16(af[c], bfr, st, 0, 0, 0);
        }
        __builtin_amdgcn_s_setprio(0);
        #pragma unroll
        for (int r = 0; r < 16; ++r) accs[r] += fmaxf(st[r], 0.f);
    }
    #pragma unroll
    for (int msk = 1; msk <= 16; msk <<= 1)
        #pragma unroll
        for (int r = 0; r < 16; ++r)
            accs[r] += __shfl_xor(accs[r], msk, 64);
    if (ln == 0) {
        #pragma unroll
        for (int r = 0; r < 16; ++r) {
            int mloc = wm2 * 32 + (r & 3) + ((r >> 2) << 3) + g5 * 4;
            red[mloc * 4 + wl2] = accs[r];
        }
    }
    __syncthreads();
    if (tid < 64)
        denp[(half * 8 + b) * Ln + mb + tid] =
            red[tid*4+0] + red[tid*4+1] + red[tid*4+2] + red[tid*4+3];
}

// ---------------- Kernel 3: recompute S, normalize, PV (in-reg P), residual --
__global__ __launch_bounds__(512) void fused_out(
    const float* __restrict__ x,
    const u16* __restrict__ BZh, const u16* __restrict__ CZh,
    const u16* __restrict__ VZTh, const float* __restrict__ denp,
    float* __restrict__ out)
{
    // [0,8K) BZs  [8K,16K) denl  [16K,112K) 3x32K stage buffers
    __shared__ __attribute__((aligned(16))) char smem[114688];
    char* const BZs = smem;
    float* const denl = (float*)(smem + 8192);
    char* const bufs = smem + 16384;
    const int tid = threadIdx.x;
    const int lane = tid & 63;
    const int ln = lane & 31;
    const int g5 = lane >> 5;
    const int w = tid >> 6;
    const int wm = w & 3;       // m-subtile within 128-m chunk
    const int wl = w >> 2;      // l-subtile within 64-l tile
    const int b = blockIdx.y;
    const int l0 = blockIdx.x * 64;
    const int wave_base = tid & ~63;

    auto stage = [&](int t) {
        char* bufc = bufs + (t % 3) * 32768;
        char* vzb = bufc + 16384;
        const int m0s = t << 7;
        #pragma unroll
        for (int it = 0; it < 2; ++it) {        // CZ [128 m][64 d]
            int j = (it << 9) + tid;
            int r = j >> 3;
            int u = (j & 7) ^ (r & 7);
            GLOAD16(CZh + ((b * Ln + m0s + r) << 6) + (u << 3),
                    bufc + ((it << 9) + wave_base) * 16);
        }
        #pragma unroll
        for (int it = 0; it < 2; ++it) {        // VZT [64 d][128 m]
            int j = (it << 9) + tid;
            int r = j >> 4;
            int u = (j & 15) ^ (r & 7);
            GLOAD16(VZTh + ((b << 6) + r) * Ln + m0s + (u << 3),
                    vzb + ((it << 9) + wave_base) * 16);
        }
    };

    // prologue: BZ tile, denominators, chunks 0 and 1
    {
        int r = tid >> 3;
        int u = (tid & 7) ^ (r & 7);
        GLOAD16(BZh + ((b * Ln + l0 + r) << 6) + (u << 3), BZs + wave_base * 16);
    }
    {
        const float4 c0 = *(const float4*)(denp + b * Ln + tid * 4);
        const float4 c1 = *(const float4*)(denp + (8 + b) * Ln + tid * 4);
        float4 dv;
        dv.x = 1.f / (c0.x + c1.x + EPS);
        dv.y = 1.f / (c0.y + c1.y + EPS);
        dv.z = 1.f / (c0.z + c1.z + EPS);
        dv.w = 1.f / (c0.w + c1.w + EPS);
        *(float4*)(denl + tid * 4) = dv;
    }
    stage(0); stage(1);
    __syncthreads();

    bf16x8 bzf[4];
    {
        const int lr = wl * 32 + ln;
        #pragma unroll
        for (int c = 0; c < 4; ++c) {
            int un = (c << 1) | g5;
            bzf[c] = *(const bf16x8*)(BZs + (lr << 7) + ((un ^ (lr & 7)) << 4));
        }
    }
    f32x16 acc0 = {}, acc1 = {};
    const int mA = wm * 32 + ln;

    for (int t = 0; t < 16; ++t) {
        if (t > 0) {
            if (t < 15) asm volatile("s_waitcnt vmcnt(4)" ::: "memory");
            else        asm volatile("s_waitcnt vmcnt(0)" ::: "memory");
            __builtin_amdgcn_s_barrier();
            POST_BARRIER_FENCE();
        }
        if (t + 2 < 16) stage(t + 2);
        const char* cz = bufs + (t % 3) * 32768;
        const char* vz = cz + 16384;
        // ---- phase A: st[m][l] = CZ . BZ^T ----
        f32x16 st = {};
        __builtin_amdgcn_s_setprio(1);
        #pragma unroll
        for (int c = 0; c < 4; ++c) {
            int un = (c << 1) | g5;
            bf16x8 a = *(const bf16x8*)(cz + (mA << 7) + ((un ^ (mA & 7)) << 4));
            st = __builtin_amdgcn_mfma_f32_32x32x16_bf16(a, bzf[c], st, 0, 0, 0);
        }
        __builtin_amdgcn_s_setprio(0);
        // ---- relu, scale by 1/den, pack to bf16 pairs ----
        const int mq0 = (t << 7) + wm * 32;
        u32 wv[8];
        #pragma unroll
        for (int q = 0; q < 4; ++q) {
            const float4 dq = *(const float4*)(denl + mq0 + q * 8 + g5 * 4);
            float p0 = fmaxf(st[q*4+0], 0.f) * dq.x;
            float p1 = fmaxf(st[q*4+1], 0.f) * dq.y;
            float p2 = fmaxf(st[q*4+2], 0.f) * dq.z;
            float p3 = fmaxf(st[q*4+3], 0.f) * dq.w;
            wv[q*2+0] = pk2(p0, p1);
            wv[q*2+1] = pk2(p2, p3);
        }
        // ---- assemble PV B-fragments in-register via half swaps ----
        u32 f0w0, f0w1, f0w2, f0w3, f1w0, f1w1, f1w2, f1w3;
        half_swap(wv[2], wv[0], f0w2, f0w0);
        half_swap(wv[3], wv[1], f0w3, f0w1);
        half_swap(wv[6], wv[4], f1w2, f1w0);
        half_swap(wv[7], wv[5], f1w3, f1w1);
        bf16x8 pf0, pf1;
        { uint4 t4; t4.x=f0w0; t4.y=f0w1; t4.z=f0w2; t4.w=f0w3; pf0 = __builtin_bit_cast(bf16x8, t4); }
        { uint4 t4; t4.x=f1w0; t4.y=f1w1; t4.z=f1w2; t4.w=f1w3; pf1 = __builtin_bit_cast(bf16x8, t4); }
        // ---- phase B: accT[d][l] += VZT . P over this wave's 32-m slice ----
        const int un00 = (wm << 2) | g5;            // c16 = 0
        const int un01 = (wm << 2) | 2 | g5;        // c16 = 1
        __builtin_amdgcn_s_setprio(1);
        {
            bf16x8 av;
            av = *(const bf16x8*)(vz + (ln << 8) + ((un00 ^ (ln & 7)) << 4));
            acc0 = __builtin_amdgcn_mfma_f32_32x32x16_bf16(av, pf0, acc0, 0, 0, 0);
            av = *(const bf16x8*)(vz + (ln << 8) + ((un01 ^ (ln & 7)) << 4));
            acc0 = __builtin_amdgcn_mfma_f32_32x32x16_bf16(av, pf1, acc0, 0, 0, 0);
            av = *(const bf16x8*)(vz + ((32 + ln) << 8) + ((un00 ^ (ln & 7)) << 4));
            acc1 = __builtin_amdgcn_mfma_f32_32x32x16_bf16(av, pf0, acc1, 0, 0, 0);
            av = *(const bf16x8*)(vz + ((32 + ln) << 8) + ((un01 ^ (ln & 7)) << 4));
            acc1 = __builtin_amdgcn_mfma_f32_32x32x16_bf16(av, pf1, acc1, 0, 0, 0);
        }
        __builtin_amdgcn_s_setprio(0);
    }

    // ---- cross-wave K-reduction over wm (4 waves), padded LDS slots ----
    __syncthreads();
    float* red = (float*)(bufs);
    constexpr int LSTR = 36;            // floats per lane slot (144B, bank-rotating)
    constexpr int SSTR = 64 * LSTR;     // floats per wave slot
    if (wm >= 2) {
        float* base = red + (wl * 2 + (wm - 2)) * SSTR + lane * LSTR;
        #pragma unroll
        for (int r = 0; r < 16; ++r) { base[r] = acc0[r]; base[16 + r] = acc1[r]; }
    }
    __syncthreads();
    if (wm < 2) {
        float* base = red + (wl * 2 + wm) * SSTR + lane * LSTR;
        #pragma unroll
        for (int r = 0; r < 16; ++r) { acc0[r] += base[r]; acc1[r] += base[16 + r]; }
    }
    if (wm == 1) {
        float* base = red + (4 + wl) * SSTR + lane * LSTR;
        #pragma unroll
        for (int r = 0; r < 16; ++r) { base[r] = acc0[r]; base[16 + r] = acc1[r]; }
    }
    __syncthreads();
    float* lout = (float*)(smem + 81920);   // [64 l][68 d-pad] f32
    if (wm == 0) {
        float* base = red + (4 + wl) * SSTR + lane * LSTR;
        #pragma unroll
        for (int r = 0; r < 16; ++r) { acc0[r] += base[r]; acc1[r] += base[16 + r]; }
        const int lrow = wl * 32 + ln;
        #pragma unroll
        for (int q = 0; q < 4; ++q) {
            const int d0 = q * 8 + g5 * 4;
            float4 v0;
            v0.x = acc0[q*4+0]; v0.y = acc0[q*4+1]; v0.z = acc0[q*4+2]; v0.w = acc0[q*4+3];
            *(float4*)(lout + lrow * 68 + d0) = v0;
            float4 v1;
            v1.x = acc1[q*4+0]; v1.y = acc1[q*4+1]; v1.z = acc1[q*4+2]; v1.w = acc1[q*4+3];
            *(float4*)(lout + lrow * 68 + 32 + d0) = v1;
        }
    }
    __syncthreads();
    {
        const int row = tid >> 3;
        const int dc = (tid & 7) * 8;
        const int g = (b * Ln + l0 + row) * 64 + dc;
        float4 o0 = *(const float4*)(lout + row * 68 + dc);
        float4 o1 = *(const float4*)(lout + row * 68 + dc + 4);
        const float4 x0 = *(const float4*)(x + g);
        const float4 x1 = *(const float4*)(x + g + 4);
        o0.x += x0.x; o0.y += x0.y; o0.z += x0.z; o0.w += x0.w;
        o1.x += x1.x; o1.y += x1.y; o1.z += x1.z; o1.w += x1.w;
        *(float4*)(out + g) = o0;
        *(float4*)(out + g + 4) = o1;
    }
}

extern "C" void kernel_launch(void* const* d_in, const int* in_sizes, int n_in,
                              void* d_out, int out_size, void* d_ws, size_t ws_size,
                              hipStream_t stream) {
    const float* x  = (const float*)d_in[0];
    const float* Bw = (const float*)d_in[1];
    const float* Bb = (const float*)d_in[2];
    const float* Cw = (const float*)d_in[3];
    const float* Cb = (const float*)d_in[4];
    const float* Vw = (const float*)d_in[5];
    const float* Vb = (const float*)d_in[6];
    float* out = (float*)d_out;
    char* wsb = (char*)d_ws;
    u16* BZh  = (u16*)wsb;                       // 2 MB
    u16* CZh  = (u16*)(wsb + (2u << 20));        // 2 MB
    u16* VZTh = (u16*)(wsb + (4u << 20));        // 2 MB
    float* denp = (float*)(wsb + (6u << 20));    // 128 KB: [2][8][2048]

    proj_k<<<dim3(256), 512, 0, stream>>>(x, Bw, Bb, Cw, Cb, Vw, Vb, BZh, CZh, VZTh);
    denom_k<<<dim3(32, 8, 2), 512, 0, stream>>>(BZh, CZh, denp);
    fused_out<<<dim3(32, 8), 512, 0, stream>>>(x, BZh, CZh, VZTh, denp, out);
}

// Round 5
// 51.700 us; speedup vs baseline: 4.6353x; 1.0409x over previous
//
#include <hip/hip_runtime.h>

typedef unsigned short u16;
typedef unsigned int u32;
typedef __bf16 bf16x8 __attribute__((ext_vector_type(8)));
typedef float f32x16 __attribute__((ext_vector_type(16)));
typedef const void __attribute__((address_space(1))) gvoid;
typedef void __attribute__((address_space(3))) lvoid;

#define GLOAD16(gp, lp) __builtin_amdgcn_global_load_lds((gvoid*)(gp), (lvoid*)(lp), 16, 0, 0)
// compiler fence after raw s_barrier: s_barrier is IntrNoMem, LDS reads may
// otherwise hoist above it and race other waves' in-flight global_load_lds.
#define POST_BARRIER_FENCE() do { __builtin_amdgcn_sched_barrier(0); asm volatile("" ::: "memory"); } while (0)

namespace {
constexpr int Ln = 2048;
constexpr float EPS = 1e-8f;
}

__device__ __forceinline__ u16 f2bf(float f) {
  __bf16 h = (__bf16)f;
  return __builtin_bit_cast(u16, h);
}

__device__ __forceinline__ u32 pk2(float lo, float hi) {
    u32 r;
    asm("v_cvt_pk_bf16_f32 %0, %1, %2" : "=v"(r) : "v"(lo), "v"(hi));
    return r;
}

// half_swap semantics: na[l<32] = b[l+32], na[l>=32] = a[l];
//                      nb[l<32] = b[l],    nb[l>=32] = a[l-32]
__device__ __forceinline__ void half_swap(u32 a, u32 b, u32& na, u32& nb) {
    u32 sa = (u32)__shfl_xor((int)a, 32, 64);
    u32 sb = (u32)__shfl_xor((int)b, 32, 64);
    int hi = (threadIdx.x & 63) >> 5;
    na = hi ? a : sb;
    nb = hi ? sa : b;
}

// ---------------- Kernel 1: projections via MFMA, no LDS ----------------
// Per wave: 32 rows. Fragments read straight from global (A-frag(M) content
// == B-frag(M^T) content: lane holds M[row=lane&31][c*16+g5*8 .. +8]).
// BZ/CZ computed as Z^T = W . x^T (D: col=l, regs=e) -> row-major 8B writes.
// VZ computed as  Z = x . Wv^T  (D: col=e, regs=l) -> VZT[d][l] 8B writes.
__global__ __launch_bounds__(256) void proj_k(
    const float* __restrict__ x,
    const float* __restrict__ Bw, const float* __restrict__ Bb,
    const float* __restrict__ Cw, const float* __restrict__ Cb,
    const float* __restrict__ Vw, const float* __restrict__ Vb,
    u16* __restrict__ BZh, u16* __restrict__ CZh, u16* __restrict__ VZTh)
{
    const int tid = threadIdx.x;
    const int ln = tid & 31;
    const int g5 = (tid >> 5) & 1;
    const int w  = tid >> 6;                      // 0..3
    const int row0 = blockIdx.x * 128 + w * 32;   // flat row base of this wave

    // weight fragments: lane holds W[e*32+ln][c*16+g5*8 .. +8]
    bf16x8 wf[3][2][4];
    const float* const Wp[3] = {Bw, Cw, Vw};
    #pragma unroll
    for (int m = 0; m < 3; ++m)
      #pragma unroll
      for (int e = 0; e < 2; ++e)
        #pragma unroll
        for (int c = 0; c < 4; ++c) {
            const float* p = Wp[m] + (e * 32 + ln) * 64 + c * 16 + g5 * 8;
            const float4 lo = *(const float4*)p;
            const float4 hi = *(const float4*)(p + 4);
            uint4 t4;
            t4.x = pk2(lo.x, lo.y); t4.y = pk2(lo.z, lo.w);
            t4.z = pk2(hi.x, hi.y); t4.w = pk2(hi.z, hi.w);
            wf[m][e][c] = __builtin_bit_cast(bf16x8, t4);
        }
    // x fragments: lane holds x[row0+ln][c*16+g5*8 .. +8]
    bf16x8 xf[4];
    {
        const float* xp = x + (row0 + ln) * 64 + g5 * 8;
        #pragma unroll
        for (int c = 0; c < 4; ++c) {
            const float4 lo = *(const float4*)(xp + c * 16);
            const float4 hi = *(const float4*)(xp + c * 16 + 4);
            uint4 t4;
            t4.x = pk2(lo.x, lo.y); t4.y = pk2(lo.z, lo.w);
            t4.z = pk2(hi.x, hi.y); t4.w = pk2(hi.z, hi.w);
            xf[c] = __builtin_bit_cast(bf16x8, t4);
        }
    }
    const int b   = row0 >> 11;
    const int l0b = row0 & 2047;
    // ---- BZ / CZ ----
    const float* const biasBC[2] = {Bb, Cb};
    u16* const outBC[2] = {BZh, CZh};
    #pragma unroll
    for (int m = 0; m < 2; ++m) {
        #pragma unroll
        for (int e = 0; e < 2; ++e) {
            f32x16 st;
            #pragma unroll
            for (int q = 0; q < 4; ++q) {   // bias folded into C: e = e*32+q*8+g5*4+j
                const float4 bv = *(const float4*)(biasBC[m] + e * 32 + q * 8 + g5 * 4);
                st[q*4+0] = bv.x; st[q*4+1] = bv.y; st[q*4+2] = bv.z; st[q*4+3] = bv.w;
            }
            #pragma unroll
            for (int c = 0; c < 4; ++c)
                st = __builtin_amdgcn_mfma_f32_32x32x16_bf16(wf[m][e][c], xf[c], st, 0, 0, 0);
            u16* op = outBC[m] + (row0 + ln) * 64 + e * 32 + g5 * 4;
            #pragma unroll
            for (int q = 0; q < 4; ++q) {
                uint2 pk;
                pk.x = pk2(st[q*4+0], st[q*4+1]);
                pk.y = pk2(st[q*4+2], st[q*4+3]);
                *(uint2*)(op + q * 8) = pk;
            }
        }
    }
    // ---- VZ -> VZT ----
    #pragma unroll
    for (int e = 0; e < 2; ++e) {
        const float vb = Vb[e * 32 + ln];
        f32x16 st;
        #pragma unroll
        for (int r = 0; r < 16; ++r) st[r] = vb;
        #pragma unroll
        for (int c = 0; c < 4; ++c)
            st = __builtin_amdgcn_mfma_f32_32x32x16_bf16(xf[c], wf[2][e][c], st, 0, 0, 0);
        u16* op = VZTh + (b * 64 + e * 32 + ln) * Ln + l0b + g5 * 4;
        #pragma unroll
        for (int q = 0; q < 4; ++q) {       // l = q*8 + g5*4 + j
            uint2 pk;
            pk.x = pk2(st[q*4+0], st[q*4+1]);
            pk.y = pk2(st[q*4+2], st[q*4+3]);
            *(uint2*)(op + q * 8) = pk;
        }
    }
}

// ---------------- Kernel 2: partial column denominators via MFMA ----------
// denp[half][b][m] = sum over l-half of relu(BZ[b,l,:] . CZ[b,m,:])
__global__ __launch_bounds__(512) void denom_k(
    const u16* __restrict__ BZh, const u16* __restrict__ CZh,
    float* __restrict__ denp)
{
    __shared__ __attribute__((aligned(16))) char smem2[49152 + 1024];
    float* const red = (float*)(smem2 + 49152);
    const int tid = threadIdx.x;
    const int lane = tid & 63;
    const int ln = lane & 31;
    const int g5 = lane >> 5;
    const int w = tid >> 6;
    const int wm2 = w & 1, wl2 = w >> 1;     // 2 m-tiles x 4 l-subtiles
    // XCD-aware swizzle: XCD k <-> batch k (512 blocks, 512%8==0, bijective)
    const int flat = (int)blockIdx.z * 256 + (int)blockIdx.y * 32 + (int)blockIdx.x;
    const int nf = (flat & 7) * 64 + (flat >> 3);
    const int b = nf >> 6;
    const int rem = nf & 63;
    const int mb = (rem & 31) * 64;
    const int half = rem >> 5;
    const int l0h = half * 1024;
    const int wave_base = tid & ~63;

    bf16x8 af[4];
    {
        const u16* cp = CZh + ((b * Ln + mb + wm2 * 32 + ln) << 6) + g5 * 8;
        #pragma unroll
        for (int c = 0; c < 4; ++c) af[c] = *(const bf16x8*)(cp + c * 16);
    }
    auto stageD = [&](int t) {
        char* buf = smem2 + (t % 3) * 16384;
        #pragma unroll
        for (int it = 0; it < 2; ++it) {
            int j = (it << 9) + tid;
            int r = j >> 3;
            int u = (j & 7) ^ (r & 7);
            GLOAD16(BZh + ((b * Ln + l0h + t * 128 + r) << 6) + (u << 3),
                    buf + ((it << 9) + wave_base) * 16);
        }
    };
    stageD(0); stageD(1);
    __syncthreads();
    float accs[16];
    #pragma unroll
    for (int r = 0; r < 16; ++r) accs[r] = 0.f;
    const int lr = wl2 * 32 + ln;
    for (int t = 0; t < 8; ++t) {
        if (t > 0) {
            if (t < 7) asm volatile("s_waitcnt vmcnt(2)" ::: "memory");
            else       asm volatile("s_waitcnt vmcnt(0)" ::: "memory");
            __builtin_amdgcn_s_barrier();
            POST_BARRIER_FENCE();
        }
        if (t + 2 < 8) stageD(t + 2);
        const char* buf = smem2 + (t % 3) * 16384;
        f32x16 st = {};
        __builtin_amdgcn_s_setprio(1);
        #pragma unroll
        for (int c = 0; c < 4; ++c) {
            int un = (c << 1) | g5;
            bf16x8 bfr = *(const bf16x8*)(buf + (lr << 7) + ((un ^ (lr & 7)) << 4));
            st = __builtin_amdgcn_mfma_f32_32x32x16_bf16(af[c], bfr, st, 0, 0, 0);
        }
        __builtin_amdgcn_s_setprio(0);
        #pragma unroll
        for (int r = 0; r < 16; ++r) accs[r] += fmaxf(st[r], 0.f);
    }
    #pragma unroll
    for (int msk = 1; msk <= 16; msk <<= 1)
        #pragma unroll
        for (int r = 0; r < 16; ++r)
            accs[r] += __shfl_xor(accs[r], msk, 64);
    if (ln == 0) {
        #pragma unroll
        for (int r = 0; r < 16; ++r) {
            int mloc = wm2 * 32 + (r & 3) + ((r >> 2) << 3) + g5 * 4;
            red[mloc * 4 + wl2] = accs[r];
        }
    }
    __syncthreads();
    if (tid < 64)
        denp[(half * 8 + b) * Ln + mb + tid] =
            red[tid*4+0] + red[tid*4+1] + red[tid*4+2] + red[tid*4+3];
}

// ---------------- Kernel 3: recompute S, normalize, PV (in-reg P), residual --
__global__ __launch_bounds__(512) void fused_out(
    const float* __restrict__ x,
    const u16* __restrict__ BZh, const u16* __restrict__ CZh,
    const u16* __restrict__ VZTh, const float* __restrict__ denp,
    float* __restrict__ out)
{
    // [0,8K) BZs  [8K,16K) denl  [16K,112K) 3x32K stage buffers
    // epilogue: red slots at [16K, 16K+8*9216) ; lout at [0, 17408)
    __shared__ __attribute__((aligned(16))) char smem[114688];
    char* const BZs = smem;
    float* const denl = (float*)(smem + 8192);
    char* const bufs = smem + 16384;
    const int tid = threadIdx.x;
    const int lane = tid & 63;
    const int ln = lane & 31;
    const int g5 = lane >> 5;
    const int w = tid >> 6;
    const int wm = w & 3;       // m-subtile within 128-m chunk
    const int wl = w >> 2;      // l-subtile within 64-l tile
    // XCD-aware swizzle: XCD k <-> batch k (256 blocks, 256%8==0, bijective)
    const int flat = (int)blockIdx.y * 32 + (int)blockIdx.x;
    const int nf = (flat & 7) * 32 + (flat >> 3);
    const int b = nf >> 5;
    const int l0 = (nf & 31) * 64;
    const int wave_base = tid & ~63;

    auto stage = [&](int t) {
        char* bufc = bufs + (t % 3) * 32768;
        char* vzb = bufc + 16384;
        const int m0s = t << 7;
        #pragma unroll
        for (int it = 0; it < 2; ++it) {        // CZ [128 m][64 d]
            int j = (it << 9) + tid;
            int r = j >> 3;
            int u = (j & 7) ^ (r & 7);
            GLOAD16(CZh + ((b * Ln + m0s + r) << 6) + (u << 3),
                    bufc + ((it << 9) + wave_base) * 16);
        }
        #pragma unroll
        for (int it = 0; it < 2; ++it) {        // VZT [64 d][128 m]
            int j = (it << 9) + tid;
            int r = j >> 4;
            int u = (j & 15) ^ (r & 7);
            GLOAD16(VZTh + ((b << 6) + r) * Ln + m0s + (u << 3),
                    vzb + ((it << 9) + wave_base) * 16);
        }
    };

    // prologue: BZ tile, denominators, chunks 0 and 1
    {
        int r = tid >> 3;
        int u = (tid & 7) ^ (r & 7);
        GLOAD16(BZh + ((b * Ln + l0 + r) << 6) + (u << 3), BZs + wave_base * 16);
    }
    {
        const float4 c0 = *(const float4*)(denp + b * Ln + tid * 4);
        const float4 c1 = *(const float4*)(denp + (8 + b) * Ln + tid * 4);
        float4 dv;
        dv.x = 1.f / (c0.x + c1.x + EPS);
        dv.y = 1.f / (c0.y + c1.y + EPS);
        dv.z = 1.f / (c0.z + c1.z + EPS);
        dv.w = 1.f / (c0.w + c1.w + EPS);
        *(float4*)(denl + tid * 4) = dv;
    }
    stage(0); stage(1);
    __syncthreads();

    bf16x8 bzf[4];
    {
        const int lr = wl * 32 + ln;
        #pragma unroll
        for (int c = 0; c < 4; ++c) {
            int un = (c << 1) | g5;
            bzf[c] = *(const bf16x8*)(BZs + (lr << 7) + ((un ^ (lr & 7)) << 4));
        }
    }
    f32x16 acc0 = {}, acc1 = {};
    const int mA = wm * 32 + ln;

    for (int t = 0; t < 16; ++t) {
        if (t > 0) {
            if (t < 15) asm volatile("s_waitcnt vmcnt(4)" ::: "memory");
            else        asm volatile("s_waitcnt vmcnt(0)" ::: "memory");
            __builtin_amdgcn_s_barrier();
            POST_BARRIER_FENCE();
        }
        if (t + 2 < 16) stage(t + 2);
        const char* cz = bufs + (t % 3) * 32768;
        const char* vz = cz + 16384;
        // ---- phase A: st[m][l] = CZ . BZ^T ----
        f32x16 st = {};
        __builtin_amdgcn_s_setprio(1);
        #pragma unroll
        for (int c = 0; c < 4; ++c) {
            int un = (c << 1) | g5;
            bf16x8 a = *(const bf16x8*)(cz + (mA << 7) + ((un ^ (mA & 7)) << 4));
            st = __builtin_amdgcn_mfma_f32_32x32x16_bf16(a, bzf[c], st, 0, 0, 0);
        }
        __builtin_amdgcn_s_setprio(0);
        // ---- relu, scale by 1/den, pack to bf16 pairs ----
        const int mq0 = (t << 7) + wm * 32;
        u32 wv[8];
        #pragma unroll
        for (int q = 0; q < 4; ++q) {
            const float4 dq = *(const float4*)(denl + mq0 + q * 8 + g5 * 4);
            float p0 = fmaxf(st[q*4+0], 0.f) * dq.x;
            float p1 = fmaxf(st[q*4+1], 0.f) * dq.y;
            float p2 = fmaxf(st[q*4+2], 0.f) * dq.z;
            float p3 = fmaxf(st[q*4+3], 0.f) * dq.w;
            wv[q*2+0] = pk2(p0, p1);
            wv[q*2+1] = pk2(p2, p3);
        }
        // ---- assemble PV B-fragments in-register via half swaps ----
        u32 f0w0, f0w1, f0w2, f0w3, f1w0, f1w1, f1w2, f1w3;
        half_swap(wv[2], wv[0], f0w2, f0w0);
        half_swap(wv[3], wv[1], f0w3, f0w1);
        half_swap(wv[6], wv[4], f1w2, f1w0);
        half_swap(wv[7], wv[5], f1w3, f1w1);
        bf16x8 pf0, pf1;
        { uint4 t4; t4.x=f0w0; t4.y=f0w1; t4.z=f0w2; t4.w=f0w3; pf0 = __builtin_bit_cast(bf16x8, t4); }
        { uint4 t4; t4.x=f1w0; t4.y=f1w1; t4.z=f1w2; t4.w=f1w3; pf1 = __builtin_bit_cast(bf16x8, t4); }
        // ---- phase B: accT[d][l] += VZT . P over this wave's 32-m slice ----
        const int un00 = (wm << 2) | g5;            // c16 = 0
        const int un01 = (wm << 2) | 2 | g5;        // c16 = 1
        __builtin_amdgcn_s_setprio(1);
        {
            bf16x8 av;
            av = *(const bf16x8*)(vz + (ln << 8) + ((un00 ^ (ln & 7)) << 4));
            acc0 = __builtin_amdgcn_mfma_f32_32x32x16_bf16(av, pf0, acc0, 0, 0, 0);
            av = *(const bf16x8*)(vz + (ln << 8) + ((un01 ^ (ln & 7)) << 4));
            acc0 = __builtin_amdgcn_mfma_f32_32x32x16_bf16(av, pf1, acc0, 0, 0, 0);
            av = *(const bf16x8*)(vz + ((32 + ln) << 8) + ((un00 ^ (ln & 7)) << 4));
            acc1 = __builtin_amdgcn_mfma_f32_32x32x16_bf16(av, pf0, acc1, 0, 0, 0);
            av = *(const bf16x8*)(vz + ((32 + ln) << 8) + ((un01 ^ (ln & 7)) << 4));
            acc1 = __builtin_amdgcn_mfma_f32_32x32x16_bf16(av, pf1, acc1, 0, 0, 0);
        }
        __builtin_amdgcn_s_setprio(0);
    }

    // ---- cross-wave K-reduction over wm (4 waves), race-free barrier plan ----
    __syncthreads();
    float* red = (float*)(bufs);
    constexpr int LSTR = 36;            // floats per lane slot (144B, bank-rotating)
    constexpr int SSTR = 64 * LSTR;     // floats per wave slot
    if (wm >= 2) {
        float* base = red + (wl * 2 + (wm - 2)) * SSTR + lane * LSTR;
        #pragma unroll
        for (int r = 0; r < 16; ++r) { base[r] = acc0[r]; base[16 + r] = acc1[r]; }
    }
    __syncthreads();
    if (wm < 2) {
        float* base = red + (wl * 2 + wm) * SSTR + lane * LSTR;
        #pragma unroll
        for (int r = 0; r < 16; ++r) { acc0[r] += base[r]; acc1[r] += base[16 + r]; }
    }
    __syncthreads();                    // slots 0..7 reads done before 4..7 rewritten
    if (wm == 1) {
        float* base = red + (4 + wl) * SSTR + lane * LSTR;
        #pragma unroll
        for (int r = 0; r < 16; ++r) { base[r] = acc0[r]; base[16 + r] = acc1[r]; }
    }
    __syncthreads();
    float* lout = (float*)(smem);       // [64 l][68 d-pad] f32, in dead BZs/denl region
    if (wm == 0) {
        float* base = red + (4 + wl) * SSTR + lane * LSTR;
        #pragma unroll
        for (int r = 0; r < 16; ++r) { acc0[r] += base[r]; acc1[r] += base[16 + r]; }
        const int lrow = wl * 32 + ln;
        #pragma unroll
        for (int q = 0; q < 4; ++q) {
            const int d0 = q * 8 + g5 * 4;
            float4 v0;
            v0.x = acc0[q*4+0]; v0.y = acc0[q*4+1]; v0.z = acc0[q*4+2]; v0.w = acc0[q*4+3];
            *(float4*)(lout + lrow * 68 + d0) = v0;
            float4 v1;
            v1.x = acc1[q*4+0]; v1.y = acc1[q*4+1]; v1.z = acc1[q*4+2]; v1.w = acc1[q*4+3];
            *(float4*)(lout + lrow * 68 + 32 + d0) = v1;
        }
    }
    __syncthreads();
    {
        const int row = tid >> 3;
        const int dc = (tid & 7) * 8;
        const int g = (b * Ln + l0 + row) * 64 + dc;
        float4 o0 = *(const float4*)(lout + row * 68 + dc);
        float4 o1 = *(const float4*)(lout + row * 68 + dc + 4);
        const float4 x0 = *(const float4*)(x + g);
        const float4 x1 = *(const float4*)(x + g + 4);
        o0.x += x0.x; o0.y += x0.y; o0.z += x0.z; o0.w += x0.w;
        o1.x += x1.x; o1.y += x1.y; o1.z += x1.z; o1.w += x1.w;
        *(float4*)(out + g) = o0;
        *(float4*)(out + g + 4) = o1;
    }
}

extern "C" void kernel_launch(void* const* d_in, const int* in_sizes, int n_in,
                              void* d_out, int out_size, void* d_ws, size_t ws_size,
                              hipStream_t stream) {
    const float* x  = (const float*)d_in[0];
    const float* Bw = (const float*)d_in[1];
    const float* Bb = (const float*)d_in[2];
    const float* Cw = (const float*)d_in[3];
    const float* Cb = (const float*)d_in[4];
    const float* Vw = (const float*)d_in[5];
    const float* Vb = (const float*)d_in[6];
    float* out = (float*)d_out;
    char* wsb = (char*)d_ws;
    u16* BZh  = (u16*)wsb;                       // 2 MB
    u16* CZh  = (u16*)(wsb + (2u << 20));        // 2 MB
    u16* VZTh = (u16*)(wsb + (4u << 20));        // 2 MB
    float* denp = (float*)(wsb + (6u << 20));    // 128 KB: [2][8][2048]

    proj_k<<<dim3(128), 256, 0, stream>>>(x, Bw, Bb, Cw, Cb, Vw, Vb, BZh, CZh, VZTh);
    denom_k<<<dim3(32, 8, 2), 512, 0, stream>>>(BZh, CZh, denp);
    fused_out<<<dim3(32, 8), 512, 0, stream>>>(x, BZh, CZh, VZTh, denp, out);
}